// Round 1
// baseline (1459.679 us; speedup 1.0000x reference)
//
#include <hip/hip_runtime.h>
#include <hip/hip_fp16.h>

#define B_  256
#define T_  2048
#define D_  128
#define H_  128
#define G_  512
#define CH  32
#define NCH (T_ / CH)

typedef __attribute__((ext_vector_type(8))) short    short8;
typedef __attribute__((ext_vector_type(4))) float    floatx4;
typedef __attribute__((ext_vector_type(2))) _Float16 half2v;

static __device__ __forceinline__ unsigned pack_bf16(float a, float b) {
  unsigned ua = __builtin_bit_cast(unsigned, a);
  unsigned ub = __builtin_bit_cast(unsigned, b);
  ua = ua + 0x7fffu + ((ua >> 16) & 1u);   // RNE to bf16
  ub = ub + 0x7fffu + ((ub >> 16) & 1u);
  return (ua >> 16) | (ub & 0xffff0000u);
}

static __device__ __forceinline__ float fdot2f(unsigned w, unsigned h, float acc) {
  return __builtin_amdgcn_fdot2(__builtin_bit_cast(half2v, w),
                                __builtin_bit_cast(half2v, h), acc, false);
}

static __device__ __forceinline__ float sigm_fast(float x) {
  float e = __builtin_amdgcn_exp2f(x * -1.44269504088896341f);
  return __builtin_amdgcn_rcpf(1.0f + e);
}
static __device__ __forceinline__ float tanh_fast(float x) {
  float e = __builtin_amdgcn_exp2f(x * 2.88539008177792681f);
  return 1.0f - 2.0f * __builtin_amdgcn_rcpf(e + 1.0f);
}

// quad_perm broadcast of lane (pat: 0x00,0x55,0xAA,0xFF -> quad lanes 0..3)
#define QBCAST(v, pat)                                                         \
  __builtin_bit_cast(float, __builtin_amdgcn_mov_dpp(                          \
      __builtin_bit_cast(int, v), (pat), 0xF, 0xF, false))

// One block per batch element. 512 threads = 8 waves.
// thread tid = (unit j = tid>>2, gate-type q = tid&3); gate row = q*128 + j.
// Whh row (f16 pairs) lives in 64 VGPRs/thread; Wih lives in 64 VGPRs/thread
// as persistent MFMA B-fragments (wave wv owns gate cols [wv*64, wv*64+64)).
__global__ __launch_bounds__(512, 2) void lstm_fused(
    const float* __restrict__ x,   const float* __restrict__ Wih,
    const float* __restrict__ Whh, const float* __restrict__ bih,
    const float* __restrict__ bhh, const float* __restrict__ Wo,
    const float* __restrict__ bo,  float* __restrict__ out)
{
  __shared__ unsigned       xs[CH][68];        // x chunk, bf16 pairs (+4 pad: banks & 16B align)
  __shared__ unsigned short xgb[CH][G_];       // xg chunk, f16, gate-permuted
  __shared__ __align__(16) unsigned hbuf[2][64]; // h ping-pong, f16 pairs (256 B each)

  const int tid  = threadIdx.x;
  const int b    = blockIdx.x;
  const int lane = tid & 63;
  const int wv   = tid >> 6;
  const int q    = tid & 3;
  const int j    = tid >> 2;
  const int grow = q * H_ + j;                 // gate row in [0,512): i,f,g,o blocks
  const int quad = lane >> 4;
  const int m16  = lane & 15;

  // ---- Whh row -> packed f16 pairs in registers (reads hit L2/L3 after block 0)
  unsigned wpk[64];
  {
    const float2* wr = (const float2*)(Whh + (size_t)grow * H_);
    #pragma unroll
    for (int k = 0; k < 64; ++k) {
      float2 v = wr[k];
      wpk[k] = __builtin_bit_cast(unsigned, __builtin_amdgcn_cvt_pkrtz(v.x, v.y));
    }
  }
  const float bias = bih[grow] + bhh[grow];

  // ---- Wih B-fragments (bf16): B[k][n]=Wih[n][k]; lane holds col n=m16, k=kf*32+quad*8..+7
  uint4 bfr[4][4];
  #pragma unroll
  for (int nt = 0; nt < 4; ++nt) {
    int row = wv * 64 + nt * 16 + m16;
    const float4* p = (const float4*)(Wih + (size_t)row * D_);
    #pragma unroll
    for (int kf = 0; kf < 4; ++kf) {
      float4 f0 = p[kf * 8 + quad * 2];
      float4 f1 = p[kf * 8 + quad * 2 + 1];
      uint4 u;
      u.x = pack_bf16(f0.x, f0.y);  u.y = pack_bf16(f0.z, f0.w);
      u.z = pack_bf16(f1.x, f1.y);  u.w = pack_bf16(f1.z, f1.w);
      bfr[nt][kf] = u;
    }
  }

  if (tid < 64) { hbuf[0][tid] = 0u; hbuf[1][tid] = 0u; }
  float c = 0.0f;
  __syncthreads();

  const float* xb = x + (size_t)b * T_ * D_;

  for (int ch = 0; ch < NCH; ++ch) {
    // ---- stage x chunk (contiguous 16 KB) as bf16 pairs into LDS
    const float4* xsrc = (const float4*)(xb + (size_t)ch * CH * D_);
    #pragma unroll
    for (int i = 0; i < 2; ++i) {
      int fi = i * 512 + tid;                  // 1024 float4 = 32 x 128 floats
      float4 v = xsrc[fi];
      int t  = fi >> 5;
      int kp = (fi & 31) * 2;
      xs[t][kp]     = pack_bf16(v.x, v.y);
      xs[t][kp + 1] = pack_bf16(v.z, v.w);
    }
    __syncthreads();

    // ---- xg = x @ Wih^T for this chunk via MFMA (A: lane m=m16, k=quad*8+i)
    #pragma unroll
    for (int mt = 0; mt < 2; ++mt) {
      short8 af[4];
      #pragma unroll
      for (int kf = 0; kf < 4; ++kf) {
        const uint4* ap = (const uint4*)&xs[mt * 16 + m16][kf * 16 + quad * 4];
        af[kf] = __builtin_bit_cast(short8, *ap);
      }
      #pragma unroll
      for (int nt = 0; nt < 4; ++nt) {
        floatx4 acc = {0.f, 0.f, 0.f, 0.f};
        #pragma unroll
        for (int kf = 0; kf < 4; ++kf)
          acc = __builtin_amdgcn_mfma_f32_16x16x32_bf16(
              af[kf], __builtin_bit_cast(short8, bfr[nt][kf]), acc, 0, 0, 0);
        int gcol = wv * 64 + nt * 16 + m16;
        int pg   = (gcol & 127) * 4 + (gcol >> 7);  // permute so reader index == tid
        #pragma unroll
        for (int r = 0; r < 4; ++r) {               // D: row=quad*4+r, col=m16 (m89 layout)
          int trow = mt * 16 + quad * 4 + r;
          xgb[trow][pg] = __half_as_ushort(__float2half(acc[r]));
        }
      }
    }
    __syncthreads();

    // ---- 32 recurrence steps
    for (int tt = 0; tt < CH; ++tt) {
      const uint4* hb4 = (const uint4*)hbuf[tt & 1];
      float a0 = bias + __half2float(__ushort_as_half(xgb[tt][tid]));
      float a1 = 0.f, a2 = 0.f, a3 = 0.f;
      #pragma unroll
      for (int jj = 0; jj < 16; ++jj) {        // 16 x ds_read_b128 broadcast + 64 dot2
        uint4 hv = hb4[jj];
        a0 = fdot2f(wpk[4 * jj + 0], hv.x, a0);
        a1 = fdot2f(wpk[4 * jj + 1], hv.y, a1);
        a2 = fdot2f(wpk[4 * jj + 2], hv.z, a2);
        a3 = fdot2f(wpk[4 * jj + 3], hv.w, a3);
      }
      float gate = (a0 + a1) + (a2 + a3);
      float av = (q == 2) ? tanh_fast(gate) : sigm_fast(gate);
      float gi = QBCAST(av, 0x00);
      float gf = QBCAST(av, 0x55);
      float gg = QBCAST(av, 0xAA);
      float go = QBCAST(av, 0xFF);
      c = gf * c + gi * gg;                    // redundant per quad, identical values
      float h = go * tanh_fast(c);
      if (q == 0)
        ((unsigned short*)hbuf[(tt & 1) ^ 1])[j] = __half_as_ushort(__float2half(h));
      __syncthreads();                         // single barrier/step (ping-pong h)
    }
  }

  // ---- out = h_last @ Wo^T + bo   (h_last sits in hbuf[0]: step 2047 wrote buf 0)
  if (tid < H_) {
    float acc = bo[tid];
    const float4* wr = (const float4*)(Wo + (size_t)tid * H_);
    const uint2* hp = (const uint2*)hbuf[0];
    #pragma unroll
    for (int k4 = 0; k4 < 32; ++k4) {
      float4 w  = wr[k4];
      uint2  hu = hp[k4];
      half2v h01 = __builtin_bit_cast(half2v, hu.x);
      half2v h23 = __builtin_bit_cast(half2v, hu.y);
      acc += w.x * (float)h01[0] + w.y * (float)h01[1]
           + w.z * (float)h23[0] + w.w * (float)h23[1];
    }
    out[(size_t)b * H_ + tid] = acc;
  }
}

extern "C" void kernel_launch(void* const* d_in, const int* in_sizes, int n_in,
                              void* d_out, int out_size, void* d_ws, size_t ws_size,
                              hipStream_t stream) {
  (void)in_sizes; (void)n_in; (void)d_ws; (void)ws_size; (void)out_size;
  const float* x   = (const float*)d_in[0];
  const float* Wih = (const float*)d_in[1];
  const float* Whh = (const float*)d_in[2];
  const float* bih = (const float*)d_in[3];
  const float* bhh = (const float*)d_in[4];
  const float* Wo  = (const float*)d_in[5];
  const float* bo  = (const float*)d_in[6];
  lstm_fused<<<B_, 512, 0, stream>>>(x, Wih, Whh, bih, bhh, Wo, bo, (float*)d_out);
}

// Round 2
// 1314.698 us; speedup vs baseline: 1.1103x; 1.1103x over previous
//
#include <hip/hip_runtime.h>
#include <hip/hip_fp16.h>

#define B_  256
#define T_  2048
#define D_  128
#define H_  128
#define CH  32
#define NCH (T_ / CH)

#define NLOG2E  (-1.4426950408889634f)   // i,f,o rows: sigm(x)=rcp(1+exp2(-x*log2e))
#define LOG2E2  ( 2.8853900817779268f)   // g rows:    tanh(x)=1-2*rcp(1+exp2(2x*log2e))

typedef __attribute__((ext_vector_type(8))) _Float16 half8v;
typedef __attribute__((ext_vector_type(4))) float    floatx4;

static __device__ __forceinline__ unsigned pkh(float a, float b) {
  return __builtin_bit_cast(unsigned, __builtin_amdgcn_cvt_pkrtz(a, b));
}
static __device__ __forceinline__ float h2f_lo(unsigned u) {
  return __half2float(__ushort_as_half((unsigned short)(u & 0xffffu)));
}
static __device__ __forceinline__ float h2f_hi(unsigned u) {
  return __half2float(__ushort_as_half((unsigned short)(u >> 16)));
}
// select v[n] for n in [0,4) -> 3 v_cndmask
#define SEL4(v, n) (((n) & 2) ? (((n) & 1) ? (v)[3] : (v)[2]) \
                              : (((n) & 1) ? (v)[1] : (v)[0]))

// One block per batch element (256 blocks = 1/CU). 512 threads = 8 waves.
// Recurrence: gates^T = Whh_s @ h^T via MFMA, M = gate rows, N-col 0..3 = h replicas.
// Wave wv owns units [wv*16, wv*16+16): M-tile mt covers gate rows mt*128+wv*16+..15.
__global__ __launch_bounds__(512, 2) void lstm_mfma(
    const float* __restrict__ x,   const float* __restrict__ Wih,
    const float* __restrict__ Whh, const float* __restrict__ bih,
    const float* __restrict__ bhh, const float* __restrict__ Wo,
    const float* __restrict__ bo,  float* __restrict__ out)
{
  __shared__ unsigned       xs[CH][68];          // x chunk, f16 pairs (+4 pad)
  __shared__ unsigned short xgf[CH][4 * H_];     // xg preact (scaled+biased), f16, [t][j*4+gt]
  __shared__ __align__(16) unsigned hbuf[2][64]; // h ping-pong, f16 pairs

  const int tid  = threadIdx.x;
  const int b    = blockIdx.x;
  const int lane = tid & 63;
  const int wv   = tid >> 6;
  const int quad = lane >> 4;
  const int m16  = lane & 15;

  // ---- Whh A-fragments, pre-scaled, persistent: wa[mt][kf] = 8 f16 of
  // Whh_s[mt*128+wv*16+m16][kf*32+quad*8 .. +7]
  uint4 wa[4][4];
  #pragma unroll
  for (int mt = 0; mt < 4; ++mt) {
    float s = (mt == 2) ? LOG2E2 : NLOG2E;
    const float4* p = (const float4*)(Whh + (size_t)(mt * 128 + wv * 16 + m16) * H_);
    #pragma unroll
    for (int kf = 0; kf < 4; ++kf) {
      float4 f0 = p[kf * 8 + quad * 2];
      float4 f1 = p[kf * 8 + quad * 2 + 1];
      uint4 u;
      u.x = pkh(f0.x * s, f0.y * s);  u.y = pkh(f0.z * s, f0.w * s);
      u.z = pkh(f1.x * s, f1.y * s);  u.w = pkh(f1.z * s, f1.w * s);
      wa[mt][kf] = u;
    }
  }

  // ---- Wih B-fragments for the input GEMM, pre-scaled by gate type (= wv>>1)
  const float sW = ((wv >> 1) == 2) ? LOG2E2 : NLOG2E;
  uint4 wb[4][4];
  float bv[4];
  #pragma unroll
  for (int nt = 0; nt < 4; ++nt) {
    int gcol = wv * 64 + nt * 16 + m16;
    const float4* p = (const float4*)(Wih + (size_t)gcol * D_);
    #pragma unroll
    for (int kf = 0; kf < 4; ++kf) {
      float4 f0 = p[kf * 8 + quad * 2];
      float4 f1 = p[kf * 8 + quad * 2 + 1];
      uint4 u;
      u.x = pkh(f0.x * sW, f0.y * sW);  u.y = pkh(f0.z * sW, f0.w * sW);
      u.z = pkh(f1.x * sW, f1.y * sW);  u.w = pkh(f1.z * sW, f1.w * sW);
      wb[nt][kf] = u;
    }
    bv[nt] = (bih[gcol] + bhh[gcol]) * sW;
  }

  if (tid < 128) hbuf[tid >> 6][tid & 63] = 0u;
  uint4 hfr[4] = {{0,0,0,0},{0,0,0,0},{0,0,0,0},{0,0,0,0}};
  float c = 0.0f;
  __syncthreads();

  const float* xb = x + (size_t)b * T_ * D_;

  for (int ch = 0; ch < NCH; ++ch) {
    // ---- stage x chunk (16 KB) as f16 pairs
    const float4* xsrc = (const float4*)(xb + (size_t)ch * CH * D_);
    #pragma unroll
    for (int i = 0; i < 2; ++i) {
      int fi = i * 512 + tid;
      float4 v = xsrc[fi];
      int t  = fi >> 5;
      int kp = (fi & 31) * 2;
      xs[t][kp]     = pkh(v.x, v.y);
      xs[t][kp + 1] = pkh(v.z, v.w);
    }
    __syncthreads();

    // ---- xg chunk: [32 t] x [512 g] = xs @ Wih_s^T (+ scaled bias), f16 out
    #pragma unroll
    for (int mt = 0; mt < 2; ++mt) {
      half8v af[4];
      #pragma unroll
      for (int kf = 0; kf < 4; ++kf)
        af[kf] = __builtin_bit_cast(half8v,
                   *(const uint4*)&xs[mt * 16 + m16][kf * 16 + quad * 4]);
      #pragma unroll
      for (int nt = 0; nt < 4; ++nt) {
        floatx4 acc = {0.f, 0.f, 0.f, 0.f};
        #pragma unroll
        for (int kf = 0; kf < 4; ++kf)
          acc = __builtin_amdgcn_mfma_f32_16x16x32_f16(
              af[kf], __builtin_bit_cast(half8v, wb[nt][kf]), acc, 0, 0, 0);
        int gcol = wv * 64 + nt * 16 + m16;
        int jc   = gcol & 127, gt = gcol >> 7;
        #pragma unroll
        for (int r = 0; r < 4; ++r) {
          int trow = mt * 16 + quad * 4 + r;
          xgf[trow][jc * 4 + gt] =
              __half_as_ushort(__float2half(acc[r] + bv[nt]));
        }
      }
    }
    __syncthreads();

    // ---- 32 recurrence steps
    for (int tt = 0; tt < CH; ++tt) {
      const int rp = (ch * CH + tt) & 1;
      unsigned long long xv = 0ull;
      if (m16 < 4) {
        // xg preacts for this lane's unit (independent of h -> issue first)
        xv = *(const unsigned long long*)&xgf[tt][(wv * 16 + quad * 4 + m16) * 4];
        #pragma unroll
        for (int kf = 0; kf < 4; ++kf)
          hfr[kf] = *(const uint4*)&hbuf[rp][kf * 16 + quad * 4];
      }
      floatx4 a0 = {0,0,0,0}, a1 = {0,0,0,0}, a2 = {0,0,0,0}, a3 = {0,0,0,0};
      #pragma unroll
      for (int kf = 0; kf < 4; ++kf) {
        half8v hb = __builtin_bit_cast(half8v, hfr[kf]);
        a0 = __builtin_amdgcn_mfma_f32_16x16x32_f16(
                 __builtin_bit_cast(half8v, wa[0][kf]), hb, a0, 0, 0, 0);
        a1 = __builtin_amdgcn_mfma_f32_16x16x32_f16(
                 __builtin_bit_cast(half8v, wa[1][kf]), hb, a1, 0, 0, 0);
        a2 = __builtin_amdgcn_mfma_f32_16x16x32_f16(
                 __builtin_bit_cast(half8v, wa[2][kf]), hb, a2, 0, 0, 0);
        a3 = __builtin_amdgcn_mfma_f32_16x16x32_f16(
                 __builtin_bit_cast(half8v, wa[3][kf]), hb, a3, 0, 0, 0);
      }
      if (m16 < 4) {
        const int n = m16;
        const int j = wv * 16 + quad * 4 + n;
        unsigned xlo = (unsigned)xv, xhi = (unsigned)(xv >> 32);
        float pi = SEL4(a0, n) + h2f_lo(xlo);
        float pf = SEL4(a1, n) + h2f_hi(xlo);
        float pg = SEL4(a2, n) + h2f_lo(xhi);
        float po = SEL4(a3, n) + h2f_hi(xhi);
        float gi = __builtin_amdgcn_rcpf(1.0f + __builtin_amdgcn_exp2f(pi));
        float gf = __builtin_amdgcn_rcpf(1.0f + __builtin_amdgcn_exp2f(pf));
        float go = __builtin_amdgcn_rcpf(1.0f + __builtin_amdgcn_exp2f(po));
        float gg = 1.0f - 2.0f * __builtin_amdgcn_rcpf(1.0f + __builtin_amdgcn_exp2f(pg));
        c = gf * c + gi * gg;
        float tc = 1.0f - 2.0f * __builtin_amdgcn_rcpf(
                       1.0f + __builtin_amdgcn_exp2f(c * LOG2E2));
        float h = go * tc;
        ((unsigned short*)hbuf[rp ^ 1])[j] = __half_as_ushort(__float2half(h));
      }
      __syncthreads();
    }
  }

  // ---- out = h_last @ Wo^T + bo   (h_last in hbuf[0]: last step wrote buf 0)
  if (tid < H_) {
    float acc = bo[tid];
    const float4* wr = (const float4*)(Wo + (size_t)tid * H_);
    const uint2* hp = (const uint2*)hbuf[0];
    #pragma unroll
    for (int k4 = 0; k4 < 32; ++k4) {
      float4 w  = wr[k4];
      uint2  hu = hp[k4];
      acc += w.x * h2f_lo(hu.x) + w.y * h2f_hi(hu.x)
           + w.z * h2f_lo(hu.y) + w.w * h2f_hi(hu.y);
    }
    out[(size_t)b * H_ + tid] = acc;
  }
}

extern "C" void kernel_launch(void* const* d_in, const int* in_sizes, int n_in,
                              void* d_out, int out_size, void* d_ws, size_t ws_size,
                              hipStream_t stream) {
  (void)in_sizes; (void)n_in; (void)d_ws; (void)ws_size; (void)out_size;
  const float* x   = (const float*)d_in[0];
  const float* Wih = (const float*)d_in[1];
  const float* Whh = (const float*)d_in[2];
  const float* bih = (const float*)d_in[3];
  const float* bhh = (const float*)d_in[4];
  const float* Wo  = (const float*)d_in[5];
  const float* bo  = (const float*)d_in[6];
  lstm_mfma<<<B_, 512, 0, stream>>>(x, Wih, Whh, bih, bhh, Wo, bo, (float*)d_out);
}